// Round 1
// baseline (444.947 us; speedup 1.0000x reference)
//
#include <hip/hip_runtime.h>

// SSIM 3D, round 4. Separable rank-1 window (u ⊗ v ⊗ t), fused W->H->D.
// Changes vs round 3:
//  - Double-buffered LDS exchange: ONE barrier per slice (20 total, was 40).
//    2 x 20480 B = 40960 B = exactly 160KiB/4 -> still 4 blocks/CU.
//    (5-phase ring x odd -> unroll 10 phases/iter so buffer parity is literal.)
//  - Software prefetch: slice i+1's 6 float4 loads issue right after slice i's
//    W-conv consumes the regs; latency hides under LDS write + barrier + H/D conv.
//  - Fused reduction: finalize kernel removed; blocks atomicAdd(double) a partial
//    and the last-arriving block writes out. setup_kernel zeroes acc/counter.
// Tile: W=128 (full row), TH=4 output rows, DSUB=16 depth -> 1024 blocks.

#define NDIM 128
#define TH 4
#define WR (TH + 4)            // 8 W-conv rows
#define DSUB 16
#define NHT (NDIM / TH)        // 32
#define NDT (NDIM / DSUB)      // 8
#define NB 4
#define NBLK (NHT * NDT * NB)  // 1024

__global__ void setup_kernel(const float* __restrict__ w, float* __restrict__ ws) {
    if (threadIdx.x == 0) {
        const float w000 = w[0];
        #pragma unroll
        for (int i = 0; i < 5; ++i) ws[i]      = w[i * 25];
        #pragma unroll
        for (int j = 0; j < 5; ++j) ws[5 + j]  = w[j * 5] / w000;
        #pragma unroll
        for (int k = 0; k < 5; ++k) ws[10 + k] = w[k] / w000;
        *(double*)(ws + 16)       = 0.0;   // global accumulator (8B-aligned: +64B)
        *(unsigned int*)(ws + 18) = 0u;    // arrival counter
    }
}

__launch_bounds__(256, 4)
__global__ void ssim_main(const float* __restrict__ img1,
                          const float* __restrict__ img2,
                          float* __restrict__ wsp,
                          float* __restrict__ out) {
    const int bid = blockIdx.x;
    const int th = bid % NHT;
    const int td = (bid / NHT) % NDT;
    const int b  = bid / (NHT * NDT);

    const int h0 = th * TH, d0 = td * DSUB;
    const float* __restrict__ x1 = img1 + (size_t)(b * 2 + 1) * NDIM * NDIM * NDIM;
    const float* __restrict__ x2 = img2 + (size_t)b * NDIM * NDIM * NDIM;

    float uW[5], vW[5], tW[5];
    #pragma unroll
    for (int i = 0; i < 5; ++i) { uW[i] = wsp[i]; vW[i] = wsp[5 + i]; tW[i] = wsp[10 + i]; }

    __shared__ float sWc[2][5][WR][NDIM];   // 40960 B exactly -> 4 blocks/CU

    const int tid  = threadIdx.x;
    // W-conv mapping: 8 rows x 32 col-groups of 4
    const int wrow = tid >> 5;
    const int wcg  = tid & 31;
    const int c0   = wcg * 4;
    const int ghw  = h0 + wrow - 2;
    // H/D mapping: 4 rows x 64 col-pairs of 2
    const int orow = tid >> 6;
    const int oc   = (tid & 63) * 2;

    float2 ring[5][5];                   // [slot][field], static indices only
    float2 accS = make_float2(0.f, 0.f);
    float4 ld[6];                        // A0,A1,A2,B0,B1,B2 (prefetched slice)

#define LOADP(IN) do {                                                         \
    const int ip_ = (IN);                                                      \
    const int dp_ = d0 - 2 + ip_;                                              \
    const float4 z_ = make_float4(0.f, 0.f, 0.f, 0.f);                         \
    ld[0]=z_; ld[1]=z_; ld[2]=z_; ld[3]=z_; ld[4]=z_; ld[5]=z_;                \
    if ((ip_ < DSUB + 4) && ((unsigned)dp_ < NDIM) && ((unsigned)ghw < NDIM)) {\
        const float* __restrict__ r1_ = x1 + ((size_t)dp_ * NDIM + ghw) * NDIM;\
        const float* __restrict__ r2_ = x2 + ((size_t)dp_ * NDIM + ghw) * NDIM;\
        if (wcg > 0)  { ld[0] = *(const float4*)(r1_ + c0 - 4);                \
                        ld[3] = *(const float4*)(r2_ + c0 - 4); }              \
        ld[1] = *(const float4*)(r1_ + c0);                                    \
        ld[4] = *(const float4*)(r2_ + c0);                                    \
        if (wcg < 31) { ld[2] = *(const float4*)(r1_ + c0 + 4);                \
                        ld[5] = *(const float4*)(r2_ + c0 + 4); }              \
    }                                                                          \
} while (0)

#define PHASE(I, P, B) do {                                                    \
    const int i_ = (I);                                                        \
    float ra[12] = {ld[0].x,ld[0].y,ld[0].z,ld[0].w,                           \
                    ld[1].x,ld[1].y,ld[1].z,ld[1].w,                           \
                    ld[2].x,ld[2].y,ld[2].z,ld[2].w};                          \
    float rb[12] = {ld[3].x,ld[3].y,ld[3].z,ld[3].w,                           \
                    ld[4].x,ld[4].y,ld[4].z,ld[4].w,                           \
                    ld[5].x,ld[5].y,ld[5].z,ld[5].w};                          \
    float m1v[4], m2v[4], q11v[4], q22v[4], q12v[4];                           \
    _Pragma("unroll")                                                          \
    for (int k_ = 0; k_ < 4; ++k_) {                                           \
        float m1_=0.f, m2_=0.f, q11_=0.f, q22_=0.f, q12_=0.f;                  \
        _Pragma("unroll")                                                      \
        for (int c_ = 0; c_ < 5; ++c_) {                                       \
            const float a_ = ra[k_ + c_ + 2], b_ = rb[k_ + c_ + 2];            \
            const float ta_ = tW[c_] * a_, tb_ = tW[c_] * b_;                  \
            m1_ += ta_; m2_ += tb_;                                            \
            q11_ += ta_ * a_; q22_ += tb_ * b_; q12_ += ta_ * b_;              \
        }                                                                      \
        m1v[k_]=m1_; m2v[k_]=m2_; q11v[k_]=q11_; q22v[k_]=q22_; q12v[k_]=q12_; \
    }                                                                          \
    LOADP(i_ + 1);  /* prefetch next slice; flies under barrier + H/D conv */  \
    *(float4*)&sWc[B][0][wrow][c0] = make_float4(m1v[0],m1v[1],m1v[2],m1v[3]); \
    *(float4*)&sWc[B][1][wrow][c0] = make_float4(m2v[0],m2v[1],m2v[2],m2v[3]); \
    *(float4*)&sWc[B][2][wrow][c0] = make_float4(q11v[0],q11v[1],q11v[2],q11v[3]);\
    *(float4*)&sWc[B][3][wrow][c0] = make_float4(q22v[0],q22v[1],q22v[2],q22v[3]);\
    *(float4*)&sWc[B][4][wrow][c0] = make_float4(q12v[0],q12v[1],q12v[2],q12v[3]);\
    __syncthreads();   /* writes to buf B visible; prev-phase reads of B done  \
                          one barrier ago (double-buffer invariant) */         \
    _Pragma("unroll")                                                          \
    for (int f_ = 0; f_ < 5; ++f_) {                                           \
        float2 F_ = make_float2(0.f, 0.f);                                     \
        _Pragma("unroll")                                                      \
        for (int r_ = 0; r_ < 5; ++r_) {                                       \
            const float2 wv_ = *(const float2*)&sWc[B][f_][orow + r_][oc];     \
            F_.x += vW[r_] * wv_.x;                                            \
            F_.y += vW[r_] * wv_.y;                                            \
        }                                                                      \
        ring[P][f_] = F_;                                                      \
    }                                                                          \
    if (i_ >= 4) {                                                             \
        float2 F0 = make_float2(0,0), F1 = F0, F2 = F0, F3 = F0, F4 = F0;      \
        _Pragma("unroll")                                                      \
        for (int j_ = 0; j_ < 5; ++j_) {                                       \
            const int s_ = ((P) + 1 + j_) % 5;                                 \
            const float uw_ = uW[j_];                                          \
            F0.x += uw_*ring[s_][0].x; F0.y += uw_*ring[s_][0].y;              \
            F1.x += uw_*ring[s_][1].x; F1.y += uw_*ring[s_][1].y;              \
            F2.x += uw_*ring[s_][2].x; F2.y += uw_*ring[s_][2].y;              \
            F3.x += uw_*ring[s_][3].x; F3.y += uw_*ring[s_][3].y;              \
            F4.x += uw_*ring[s_][4].x; F4.y += uw_*ring[s_][4].y;              \
        }                                                                      \
        {                                                                      \
            const float mu1 = F0.x, mu2 = F1.x;                                \
            const float m11 = mu1*mu1, m22 = mu2*mu2, m12 = mu1*mu2;           \
            const float num = (2.f*m12 + 1e-4f) * (2.f*(F4.x - m12) + 9e-4f);  \
            const float den = (m11 + m22 + 1e-4f) *                            \
                              ((F2.x - m11) + (F3.x - m22) + 9e-4f);           \
            accS.x += __fdividef(num, den);                                    \
        }                                                                      \
        {                                                                      \
            const float mu1 = F0.y, mu2 = F1.y;                                \
            const float m11 = mu1*mu1, m22 = mu2*mu2, m12 = mu1*mu2;           \
            const float num = (2.f*m12 + 1e-4f) * (2.f*(F4.y - m12) + 9e-4f);  \
            const float den = (m11 + m22 + 1e-4f) *                            \
                              ((F2.y - m11) + (F3.y - m22) + 9e-4f);           \
            accS.y += __fdividef(num, den);                                    \
        }                                                                      \
    }                                                                          \
} while (0)

    // 20 slices: d0-2 .. d0+17. 10 phases per iter so LDS buffer parity (B)
    // stays a compile-time literal while the D-ring slot (P) cycles mod 5.
    LOADP(0);
    for (int io = 0; io < 2; ++io) {
        const int ib = io * 10;
        PHASE(ib + 0, 0, 0);
        PHASE(ib + 1, 1, 1);
        PHASE(ib + 2, 2, 0);
        PHASE(ib + 3, 3, 1);
        PHASE(ib + 4, 4, 0);
        PHASE(ib + 5, 0, 1);
        PHASE(ib + 6, 1, 0);
        PHASE(ib + 7, 2, 1);
        PHASE(ib + 8, 3, 0);
        PHASE(ib + 9, 4, 1);
    }
#undef PHASE
#undef LOADP

    float acc = accS.x + accS.y;
    #pragma unroll
    for (int off = 32; off > 0; off >>= 1)
        acc += __shfl_down(acc, off, 64);
    __syncthreads();                      // all LDS reads done; reuse sWc
    float* sred = &sWc[0][0][0][0];
    if ((tid & 63) == 0) sred[tid >> 6] = acc;
    __syncthreads();
    if (tid == 0) {
        const float bsum = sred[0] + sred[1] + sred[2] + sred[3];
        double* accg      = (double*)(wsp + 16);
        unsigned int* cnt = (unsigned int*)(wsp + 18);
        atomicAdd(accg, (double)bsum);
        __threadfence();
        const unsigned int prev = atomicAdd(cnt, 1u);
        if (prev == (unsigned int)(NBLK - 1)) {
            const double total = atomicAdd(accg, 0.0);   // coherent read-back
            out[0] = 1.0f - (float)(total / (double)(4LL * NDIM * NDIM * NDIM));
        }
    }
}

extern "C" void kernel_launch(void* const* d_in, const int* in_sizes, int n_in,
                              void* d_out, int out_size, void* d_ws, size_t ws_size,
                              hipStream_t stream) {
    const float* img1 = (const float*)d_in[0];   // (4,2,128,128,128) fp32
    const float* img2 = (const float*)d_in[1];   // (4,1,128,128,128) fp32
    const float* win  = (const float*)d_in[2];   // (1,1,5,5,5) fp32
    float* out = (float*)d_out;
    float* ws  = (float*)d_ws;                   // [0..15] wfac, +16 dbl acc, +18 cnt

    hipLaunchKernelGGL(setup_kernel, dim3(1), dim3(64), 0, stream, win, ws);
    hipLaunchKernelGGL(ssim_main, dim3(NBLK), dim3(256), 0, stream,
                       img1, img2, ws, out);
}

// Round 2
// 429.774 us; speedup vs baseline: 1.0353x; 1.0353x over previous
//
#include <hip/hip_runtime.h>

// SSIM 3D, round 5. Separable rank-1 window (u ⊗ v ⊗ t), fused W->H->D.
// Round 4 post-mortem: software prefetch (ld[6] live across barrier + H/D conv)
// blew the 128-VGPR cap of __launch_bounds__(256,4) -> per-phase scratch spills
// (WRITE_SIZE 16MB -> 598MB, VALUBusy 53% -> 10%). Round 5 reverts the prefetch
// ONLY, keeping the two sound round-4 changes:
//  - Double-buffered LDS exchange: ONE barrier per slice (20 total, was 40 in r3).
//    2 x 20480 B = 40960 B = exactly 160KiB/4 -> still 4 blocks/CU.
//  - Fused reduction: blocks atomicAdd(double); last-arriving block writes out.
// Loads are back at phase head, consumed immediately (round-3 register shape,
// 64 VGPR, no scratch).
// Tile: W=128 (full row), TH=4 output rows, DSUB=16 depth -> 1024 blocks.

#define NDIM 128
#define TH 4
#define WR (TH + 4)            // 8 W-conv rows
#define DSUB 16
#define NHT (NDIM / TH)        // 32
#define NDT (NDIM / DSUB)      // 8
#define NB 4
#define NBLK (NHT * NDT * NB)  // 1024

__global__ void setup_kernel(const float* __restrict__ w, float* __restrict__ ws) {
    if (threadIdx.x == 0) {
        const float w000 = w[0];
        #pragma unroll
        for (int i = 0; i < 5; ++i) ws[i]      = w[i * 25];
        #pragma unroll
        for (int j = 0; j < 5; ++j) ws[5 + j]  = w[j * 5] / w000;
        #pragma unroll
        for (int k = 0; k < 5; ++k) ws[10 + k] = w[k] / w000;
        *(double*)(ws + 16)       = 0.0;   // global accumulator
        *(unsigned int*)(ws + 18) = 0u;    // arrival counter
    }
}

__launch_bounds__(256, 4)
__global__ void ssim_main(const float* __restrict__ img1,
                          const float* __restrict__ img2,
                          float* __restrict__ wsp,
                          float* __restrict__ out) {
    const int bid = blockIdx.x;
    const int th = bid % NHT;
    const int td = (bid / NHT) % NDT;
    const int b  = bid / (NHT * NDT);

    const int h0 = th * TH, d0 = td * DSUB;
    const float* __restrict__ x1 = img1 + (size_t)(b * 2 + 1) * NDIM * NDIM * NDIM;
    const float* __restrict__ x2 = img2 + (size_t)b * NDIM * NDIM * NDIM;

    float uW[5], vW[5], tW[5];
    #pragma unroll
    for (int i = 0; i < 5; ++i) { uW[i] = wsp[i]; vW[i] = wsp[5 + i]; tW[i] = wsp[10 + i]; }

    __shared__ float sWc[2][5][WR][NDIM];   // 40960 B exactly -> 4 blocks/CU

    const int tid  = threadIdx.x;
    // W-conv mapping: 8 rows x 32 col-groups of 4
    const int wrow = tid >> 5;
    const int wcg  = tid & 31;
    const int c0   = wcg * 4;
    const int ghw  = h0 + wrow - 2;
    // H/D mapping: 4 rows x 64 col-pairs of 2
    const int orow = tid >> 6;
    const int oc   = (tid & 63) * 2;

    float2 ring[5][5];                   // [slot][field], static indices only
    float2 accS = make_float2(0.f, 0.f);

#define PHASE(I, P, B) do {                                                    \
    const int i_ = (I);                                                        \
    const int d_ = d0 - 2 + i_;                                                \
    float4 A0 = make_float4(0,0,0,0), A1 = A0, A2 = A0;                        \
    float4 B0 = A0, B1 = A0, B2 = A0;                                          \
    if (((unsigned)d_ < NDIM) && ((unsigned)ghw < NDIM)) {                     \
        const float* __restrict__ r1_ = x1 + ((size_t)d_ * NDIM + ghw) * NDIM; \
        const float* __restrict__ r2_ = x2 + ((size_t)d_ * NDIM + ghw) * NDIM; \
        if (wcg > 0)  { A0 = *(const float4*)(r1_ + c0 - 4);                   \
                        B0 = *(const float4*)(r2_ + c0 - 4); }                 \
        A1 = *(const float4*)(r1_ + c0);                                       \
        B1 = *(const float4*)(r2_ + c0);                                       \
        if (wcg < 31) { A2 = *(const float4*)(r1_ + c0 + 4);                   \
                        B2 = *(const float4*)(r2_ + c0 + 4); }                 \
    }                                                                          \
    float ra[12] = {A0.x,A0.y,A0.z,A0.w, A1.x,A1.y,A1.z,A1.w,                  \
                    A2.x,A2.y,A2.z,A2.w};                                      \
    float rb[12] = {B0.x,B0.y,B0.z,B0.w, B1.x,B1.y,B1.z,B1.w,                  \
                    B2.x,B2.y,B2.z,B2.w};                                      \
    float m1v[4], m2v[4], q11v[4], q22v[4], q12v[4];                           \
    _Pragma("unroll")                                                          \
    for (int k_ = 0; k_ < 4; ++k_) {                                           \
        float m1_=0.f, m2_=0.f, q11_=0.f, q22_=0.f, q12_=0.f;                  \
        _Pragma("unroll")                                                      \
        for (int c_ = 0; c_ < 5; ++c_) {                                       \
            const float a_ = ra[k_ + c_ + 2], b_ = rb[k_ + c_ + 2];            \
            const float ta_ = tW[c_] * a_, tb_ = tW[c_] * b_;                  \
            m1_ += ta_; m2_ += tb_;                                            \
            q11_ += ta_ * a_; q22_ += tb_ * b_; q12_ += ta_ * b_;              \
        }                                                                      \
        m1v[k_]=m1_; m2v[k_]=m2_; q11v[k_]=q11_; q22v[k_]=q22_; q12v[k_]=q12_; \
    }                                                                          \
    *(float4*)&sWc[B][0][wrow][c0] = make_float4(m1v[0],m1v[1],m1v[2],m1v[3]); \
    *(float4*)&sWc[B][1][wrow][c0] = make_float4(m2v[0],m2v[1],m2v[2],m2v[3]); \
    *(float4*)&sWc[B][2][wrow][c0] = make_float4(q11v[0],q11v[1],q11v[2],q11v[3]);\
    *(float4*)&sWc[B][3][wrow][c0] = make_float4(q22v[0],q22v[1],q22v[2],q22v[3]);\
    *(float4*)&sWc[B][4][wrow][c0] = make_float4(q12v[0],q12v[1],q12v[2],q12v[3]);\
    __syncthreads();   /* writes to buf B visible; prior reads of buf B        \
                          finished one barrier ago (double-buffer invariant) */\
    _Pragma("unroll")                                                          \
    for (int f_ = 0; f_ < 5; ++f_) {                                           \
        float2 F_ = make_float2(0.f, 0.f);                                     \
        _Pragma("unroll")                                                      \
        for (int r_ = 0; r_ < 5; ++r_) {                                       \
            const float2 wv_ = *(const float2*)&sWc[B][f_][orow + r_][oc];     \
            F_.x += vW[r_] * wv_.x;                                            \
            F_.y += vW[r_] * wv_.y;                                            \
        }                                                                      \
        ring[P][f_] = F_;                                                      \
    }                                                                          \
    if (i_ >= 4) {                                                             \
        float2 F0 = make_float2(0,0), F1 = F0, F2 = F0, F3 = F0, F4 = F0;      \
        _Pragma("unroll")                                                      \
        for (int j_ = 0; j_ < 5; ++j_) {                                       \
            const int s_ = ((P) + 1 + j_) % 5;                                 \
            const float uw_ = uW[j_];                                          \
            F0.x += uw_*ring[s_][0].x; F0.y += uw_*ring[s_][0].y;              \
            F1.x += uw_*ring[s_][1].x; F1.y += uw_*ring[s_][1].y;              \
            F2.x += uw_*ring[s_][2].x; F2.y += uw_*ring[s_][2].y;              \
            F3.x += uw_*ring[s_][3].x; F3.y += uw_*ring[s_][3].y;              \
            F4.x += uw_*ring[s_][4].x; F4.y += uw_*ring[s_][4].y;              \
        }                                                                      \
        {                                                                      \
            const float mu1 = F0.x, mu2 = F1.x;                                \
            const float m11 = mu1*mu1, m22 = mu2*mu2, m12 = mu1*mu2;           \
            const float num = (2.f*m12 + 1e-4f) * (2.f*(F4.x - m12) + 9e-4f);  \
            const float den = (m11 + m22 + 1e-4f) *                            \
                              ((F2.x - m11) + (F3.x - m22) + 9e-4f);           \
            accS.x += __fdividef(num, den);                                    \
        }                                                                      \
        {                                                                      \
            const float mu1 = F0.y, mu2 = F1.y;                                \
            const float m11 = mu1*mu1, m22 = mu2*mu2, m12 = mu1*mu2;           \
            const float num = (2.f*m12 + 1e-4f) * (2.f*(F4.y - m12) + 9e-4f);  \
            const float den = (m11 + m22 + 1e-4f) *                            \
                              ((F2.y - m11) + (F3.y - m22) + 9e-4f);           \
            accS.y += __fdividef(num, den);                                    \
        }                                                                      \
    }                                                                          \
} while (0)

    // 20 slices: d0-2 .. d0+17. 10 phases per iter so LDS buffer parity (B)
    // stays a compile-time literal while the D-ring slot (P) cycles mod 5.
    for (int io = 0; io < 2; ++io) {
        const int ib = io * 10;
        PHASE(ib + 0, 0, 0);
        PHASE(ib + 1, 1, 1);
        PHASE(ib + 2, 2, 0);
        PHASE(ib + 3, 3, 1);
        PHASE(ib + 4, 4, 0);
        PHASE(ib + 5, 0, 1);
        PHASE(ib + 6, 1, 0);
        PHASE(ib + 7, 2, 1);
        PHASE(ib + 8, 3, 0);
        PHASE(ib + 9, 4, 1);
    }
#undef PHASE

    float acc = accS.x + accS.y;
    #pragma unroll
    for (int off = 32; off > 0; off >>= 1)
        acc += __shfl_down(acc, off, 64);
    __syncthreads();                      // all LDS reads done; reuse sWc
    float* sred = &sWc[0][0][0][0];
    if ((tid & 63) == 0) sred[tid >> 6] = acc;
    __syncthreads();
    if (tid == 0) {
        const float bsum = sred[0] + sred[1] + sred[2] + sred[3];
        double* accg      = (double*)(wsp + 16);
        unsigned int* cnt = (unsigned int*)(wsp + 18);
        atomicAdd(accg, (double)bsum);
        __threadfence();
        const unsigned int prev = atomicAdd(cnt, 1u);
        if (prev == (unsigned int)(NBLK - 1)) {
            const double total = atomicAdd(accg, 0.0);   // coherent read-back
            out[0] = 1.0f - (float)(total / (double)(4LL * NDIM * NDIM * NDIM));
        }
    }
}

extern "C" void kernel_launch(void* const* d_in, const int* in_sizes, int n_in,
                              void* d_out, int out_size, void* d_ws, size_t ws_size,
                              hipStream_t stream) {
    const float* img1 = (const float*)d_in[0];   // (4,2,128,128,128) fp32
    const float* img2 = (const float*)d_in[1];   // (4,1,128,128,128) fp32
    const float* win  = (const float*)d_in[2];   // (1,1,5,5,5) fp32
    float* out = (float*)d_out;
    float* ws  = (float*)d_ws;                   // [0..15] wfac, +16 dbl acc, +18 cnt

    hipLaunchKernelGGL(setup_kernel, dim3(1), dim3(64), 0, stream, win, ws);
    hipLaunchKernelGGL(ssim_main, dim3(NBLK), dim3(256), 0, stream,
                       img1, img2, ws, out);
}